// Round 3
// baseline (298.519 us; speedup 1.0000x reference)
//
#include <hip/hip_runtime.h>
#include <hip/hip_bf16.h>

// Conv2D 3x3 s1 p1: x[8,16,512,512] f32, w[16,144] f32 -> out[8,16,512,512] f32
//
// R6: two-kernel split.
//  K1 prep: streaming transform x (f32 NCHW) -> xt (bf16 NHWC, 64 MiB in d_ws),
//    with channel-half swizzle s(w)=(w>>2)&1 baked into layout (LDS bank spread);
//    also packs weights to wpk[co][k=tap*16+ci, padded 160] bf16 and fills a
//    zero page (OOB staging source).
//  K2 conv: implicit GEMM on bf16 MFMA 16x16x32, TW=32 TH=16, LDS [18][34][16]
//    staged via global_load_lds dwordx4 (NO VALU transpose, NO VGPR payload —
//    the structural fix for the staging-overhead bound seen R3-R5). OOB lanes
//    source from the zero page (no exec masking). 19.6 KB LDS -> 8 blocks/CU,
//    __launch_bounds__(256,8); f-outer MFMA loop keeps 1 afrag live (fits 64
//    unified VGPR+AGPR). Weights: 5 L2-hot dwordx4 instead of 40 scalar+cvt.
//  Fallback: R5 single kernel if ws_size too small.

#define IH 512
#define IW 512
#define CI 16
#define CO 16
#define TH 16
#define TW 32
#define LROWS (TH + 2)   // 18
#define LCOLS (TW + 2)   // 34
#define ROWB  (LCOLS * CI * 2)          // 1088 bytes per LDS row
#define NCHUNK (LROWS * LCOLS * 2)      // 1224 16B chunks (2 per pixel)

// workspace layout (bytes)
#define XT_OFF   0
#define XT_BYTES ((size_t)8 * IH * IW * CI * 2)        // 67,108,864
#define ZP_OFF   XT_BYTES                               // 4 KB zero page
#define ZP_BYTES 4096
#define WPK_OFF  (XT_BYTES + ZP_BYTES)                  // 16 x 160 bf16
#define WPK_BYTES 5120
#define WS_NEED  (WPK_OFF + (size_t)WPK_BYTES)

typedef short short8  __attribute__((ext_vector_type(8)));
typedef short short4v __attribute__((ext_vector_type(4)));
typedef float f32x4   __attribute__((ext_vector_type(4)));
typedef unsigned int uint4v __attribute__((ext_vector_type(4)));

__device__ __forceinline__ short f32_to_bf16_bits(float v) {
    __hip_bfloat16 b = __float2bfloat16(v);   // RNE
    return __builtin_bit_cast(short, b);
}

__device__ __forceinline__ void gload_lds16(const void* g, void* l) {
    __builtin_amdgcn_global_load_lds(
        (const __attribute__((address_space(1))) void*)g,
        (__attribute__((address_space(3))) void*)l, 16, 0, 0);
}

// ---------------------------------------------------------------------------
// K1: x f32 NCHW -> xt bf16 NHWC (half-swizzled), + zero page + packed weights
// ---------------------------------------------------------------------------
__global__ __launch_bounds__(256, 4)
void conv_prep(const float* __restrict__ x, const float* __restrict__ wgt,
               char* __restrict__ ws) {
    short* xt    = (short*)(ws + XT_OFF);
    char*  zpage = ws + ZP_OFF;
    short* wpk   = (short*)(ws + WPK_OFF);

    const int tid = threadIdx.x;
    const int p   = blockIdx.x * 256 + tid;   // 524,288 4-pixel chunks total
    const int n   = p >> 16;                  // 512*128 chunks per image
    const int rem = p & 65535;
    const int h   = rem >> 7;
    const int wq  = rem & 127;
    const int w0  = wq * 4;
    const int s   = wq & 1;                   // = (w0>>2)&1, uniform over 4 px

    const float* src = x + (size_t)n * CI * IH * IW + (size_t)h * IW + w0;
    f32x4 v[16];
#pragma unroll
    for (int c = 0; c < 16; ++c)
        v[c] = *(const f32x4*)(src + (size_t)c * IH * IW);

    short* dst = xt + ((size_t)(n * IH + h) * IW + w0) * CI;
#pragma unroll
    for (int jj = 0; jj < 4; ++jj) {
        unsigned int dl[8];                   // logical ch-pair dwords
#pragma unroll
        for (int k = 0; k < 8; ++k) {
            const unsigned lo = (unsigned short)f32_to_bf16_bits(v[2 * k][jj]);
            const unsigned hi = (unsigned short)f32_to_bf16_bits(v[2 * k + 1][jj]);
            dl[k] = lo | (hi << 16);
        }
        uint4v A = {dl[0], dl[1], dl[2], dl[3]};
        uint4v B = {dl[4], dl[5], dl[6], dl[7]};
        uint4v first  = s ? B : A;            // memory half m holds logical half m^s
        uint4v second = s ? A : B;
        uint4v* o = (uint4v*)(dst + (size_t)jj * CI);
        o[0] = first;
        o[1] = second;
    }

    if (blockIdx.x == 0) {
        // zero page: 256 threads x 16 B = 4 KB
        *(uint4v*)(zpage + tid * 16) = (uint4v){0, 0, 0, 0};
        // packed weights: wpk[co][k], k = tap*16+ci padded to 160
#pragma unroll
        for (int i = 0; i < 10; ++i) {
            const int e  = i * 256 + tid;     // 2560 entries
            const int co = e & 15;
            const int k  = e >> 4;
            float val = 0.0f;
            if (k < 144) {
                const int ci  = k & 15;
                const int tap = k >> 4;
                val = wgt[co * 144 + ci * 9 + tap];
            }
            wpk[co * 160 + k] = f32_to_bf16_bits(val);
        }
    }
}

// ---------------------------------------------------------------------------
// K2: conv via global_load_lds staging from xt
// ---------------------------------------------------------------------------
__global__ __launch_bounds__(256, 8)
void conv3x3_lds(const char* __restrict__ ws, float* __restrict__ out) {
    __shared__ short lds[LROWS * LCOLS * CI];   // 19,584 B -> 8 blocks/CU

    const short* xt    = (const short*)(ws + XT_OFF);
    const char*  zpage = ws + ZP_OFF;
    const short* wpk   = (const short*)(ws + WPK_OFF);

    const int tid  = threadIdx.x;
    const int wave = tid >> 6;
    const int lane = tid & 63;
    const int quad = lane >> 4;
    const int l15  = lane & 15;

    // XCD swizzle: image fastest (1 image per XCD under round-robin)
    const int bid   = blockIdx.x;
    const int n     = bid & 7;
    const int t     = bid >> 3;
    const int wbase = (t & 15) * TW;     // 16 tiles in x
    const int hbase = (t >> 4) * TH;     // 32 tiles in y

    // ---- staging: 1224 chunks of 16 B; 1024 via global_load_lds (4 iters),
    //      tail 200 via reg+ds_write. OOB chunks source the zero page. ----
#pragma unroll
    for (int it = 0; it < 4; ++it) {
        const int c   = it * 256 + tid;
        const int row = c / 68;              // 68 chunks per LDS row
        const int o   = c - row * 68;
        const int gh  = hbase - 1 + row;
        const int gw  = wbase - 1 + (o >> 1);
        const bool ok = ((unsigned)gh < (unsigned)IH) && ((unsigned)gw < (unsigned)IW);
        const char* g = ok
            ? (const char*)(xt + (((size_t)(n * IH + gh) * IW + gw) * CI + (o & 1) * 8))
            : zpage;
        // wave-uniform LDS base; HW adds lane*16
        char* l = (char*)lds + (size_t)(it * 256 + wave * 64) * 16;
        gload_lds16(g, l);
    }
    if (tid < 200) {
        const int c   = 1024 + tid;
        const int row = c / 68;
        const int o   = c - row * 68;
        const int gh  = hbase - 1 + row;
        const int gw  = wbase - 1 + (o >> 1);
        const bool ok = ((unsigned)gh < (unsigned)IH) && ((unsigned)gw < (unsigned)IW);
        const char* g = ok
            ? (const char*)(xt + (((size_t)(n * IH + gh) * IW + gw) * CI + (o & 1) * 8))
            : zpage;
        const uint4v v = *(const uint4v*)g;
        *(uint4v*)((char*)lds + (size_t)c * 16) = v;   // per-lane ds_write_b128
    }

    // ---- per-f tap geometry (depends only on quad) ----
    const int q = quad & 1;
    int kh_[5], kw_[5];
#pragma unroll
    for (int f = 0; f < 5; ++f) {
        const int tap = (f < 4) ? (f * 2 + (quad >> 1)) : 8;
        kh_[f] = tap / 3;
        kw_[f] = tap - (tap / 3) * 3;
    }

    __syncthreads();   // drains vmcnt (global_load_lds) + lgkm

    // ---- MFMA main: f outer (1 afrag live), 4 rows x 2 wsegs inner ----
    f32x4 acc[4][2];
#pragma unroll
    for (int r = 0; r < 4; ++r)
#pragma unroll
        for (int c4 = 0; c4 < 2; ++c4)
            acc[r][c4] = (f32x4){0.f, 0.f, 0.f, 0.f};

    const short* wp = wpk + l15 * 160 + quad * 8;
#pragma unroll
    for (int f = 0; f < 5; ++f) {
        const short8 afrag = *(const short8*)(wp + f * 32);   // dwordx4, L2-hot
#pragma unroll
        for (int r = 0; r < 4; ++r) {
            const int row = wave * 4 + r + kh_[f];
#pragma unroll
            for (int c4 = 0; c4 < 2; ++c4) {
                const int col = c4 * 16 + l15 + kw_[f];
                const int s   = ((col + 31) >> 2) & 1;        // bit2 of global w
                const int m   = q ^ s;
                const short8 b = *(const short8*)&lds[row * (LCOLS * CI) + col * CI + m * 8];
                acc[r][c4] = __builtin_amdgcn_mfma_f32_16x16x32_bf16(afrag, b, acc[r][c4], 0, 0, 0);
            }
        }
    }

    // ---- store: C/D col = l15 = pixel, row = quad*4+reg = co ----
    float* on = out + (size_t)n * CO * IH * IW;
#pragma unroll
    for (int r = 0; r < 4; ++r) {
        const int gh = hbase + wave * 4 + r;
#pragma unroll
        for (int c4 = 0; c4 < 2; ++c4) {
            const int gw = wbase + c4 * 16 + l15;
#pragma unroll
            for (int reg = 0; reg < 4; ++reg) {
                const int co = quad * 4 + reg;
                on[((size_t)co * IH + gh) * IW + gw] = acc[r][c4][reg];
            }
        }
    }
}

// ---------------------------------------------------------------------------
// Fallback (R5 kernel, used only if workspace is too small)
// ---------------------------------------------------------------------------
struct ItemInfo {
    const float* src;
    int pb, ws, cg;
    bool ok;
};

__device__ __forceinline__ ItemInfo item_info(int i, int hbase, int wbase,
                                              const float* __restrict__ xn) {
    ItemInfo t;
    t.ws = i & 7;
    t.cg = (i >> 3) & 3;
    const int row = i >> 5;
    const int gh  = hbase - 1 + row;
    t.ok  = (unsigned)gh < (unsigned)IH;
    t.src = xn + ((size_t)(t.cg * 4) * IH + gh) * IW + (wbase + 4 * t.ws);
    t.pb  = row * LCOLS + 1 + 4 * t.ws;
    return t;
}

__device__ __forceinline__ void item_load(const ItemInfo& t, f32x4 v[4]) {
    if (t.ok) {
#pragma unroll
        for (int jj = 0; jj < 4; ++jj)
            v[jj] = *(const f32x4*)(t.src + (size_t)jj * IH * IW);
    }
}

__device__ __forceinline__ void item_store(const ItemInfo& t, const f32x4 v[4],
                                           short* lds) {
    short4v pk[4];
    if (t.ok) {
#pragma unroll
        for (int j = 0; j < 4; ++j)
#pragma unroll
            for (int jj = 0; jj < 4; ++jj)
                pk[j][jj] = f32_to_bf16_bits(v[jj][j]);
    } else {
#pragma unroll
        for (int j = 0; j < 4; ++j) pk[j] = (short4v){0, 0, 0, 0};
    }
#pragma unroll
    for (int k = 0; k < 4; ++k) {
        const int j     = (k + t.ws) & 3;
        const int pixel = t.pb + j;
        const int slot  = t.cg ^ ((pixel >> 1) & 2);
        *(short4v*)&lds[pixel * 16 + slot * 4] = pk[j];
    }
}

__global__ __launch_bounds__(256, 6)
void conv3x3_mfma_fb(const float* __restrict__ x, const float* __restrict__ wgt,
                     float* __restrict__ out) {
    __shared__ short lds[LROWS * LCOLS * CI];

    const int tid  = threadIdx.x;
    const int wave = tid >> 6;
    const int lane = tid & 63;
    const int quad = lane >> 4;
    const int l15  = lane & 15;

    const int bid   = blockIdx.x;
    const int n     = bid & 7;
    const int t     = bid >> 3;
    const int wbase = (t & 15) * TW;
    const int hbase = (t >> 4) * TH;

    const float* xn = x + (size_t)n * CI * IH * IW;

    ItemInfo t0 = item_info(tid,       hbase, wbase, xn);
    ItemInfo t1 = item_info(tid + 256, hbase, wbase, xn);
    f32x4 v0[4], v1[4];
    item_load(t0, v0);
    item_load(t1, v1);
    item_store(t0, v0, lds);
    const bool has2 = tid < (LROWS * (TW / 4) * 4 - 512);
    ItemInfo t2 = item_info(has2 ? (tid + 512) : tid, hbase, wbase, xn);
    if (has2) item_load(t2, v0);
    item_store(t1, v1, lds);
    if (has2) item_store(t2, v0, lds);

    if (tid < 144) {
        const int cg4  = tid & 3;
        const int col2 = (tid >> 2) & 1;
        const int row  = tid >> 3;
        const int c    = col2 ? (LCOLS - 1) : 0;
        const int gh   = hbase - 1 + row;
        const int gw   = wbase - 1 + c;
        const bool ok  = ((unsigned)gh < (unsigned)IH) && ((unsigned)gw < (unsigned)IW);
        short4v pk;
#pragma unroll
        for (int j = 0; j < 4; ++j) {
            const float v = ok ? xn[((size_t)(cg4 * 4 + j) * IH + gh) * IW + gw] : 0.0f;
            pk[j] = f32_to_bf16_bits(v);
        }
        const int pixel = row * LCOLS + c;
        const int slot  = cg4 ^ ((pixel >> 1) & 2);
        *(short4v*)&lds[pixel * 16 + slot * 4] = pk;
    }

    short8 afrag[5];
#pragma unroll
    for (int f = 0; f < 5; ++f) {
#pragma unroll
        for (int j = 0; j < 8; ++j) {
            const int k = f * 32 + quad * 8 + j;
            float val = 0.0f;
            if (k < 144) {
                const int ci  = k & 15;
                const int tap = k >> 4;
                val = wgt[l15 * 144 + ci * 9 + tap];
            }
            afrag[f][j] = f32_to_bf16_bits(val);
        }
    }
    __syncthreads();

    const int q = quad & 1;
    int doff[5];
#pragma unroll
    for (int f = 0; f < 5; ++f) {
        const int tap = (f < 4) ? (f * 2 + (quad >> 1)) : 8;
        const int kh  = tap / 3;
        const int kw  = tap - kh * 3;
        doff[f] = kh * LCOLS + kw;
    }

    f32x4 acc[4][2];
#pragma unroll
    for (int r = 0; r < 4; ++r)
#pragma unroll
        for (int c4 = 0; c4 < 2; ++c4)
            acc[r][c4] = (f32x4){0.f, 0.f, 0.f, 0.f};

#pragma unroll
    for (int r = 0; r < 4; ++r) {
        const int hl = wave * 4 + r;
#pragma unroll
        for (int c4 = 0; c4 < 2; ++c4) {
            const int wl    = c4 * 16 + l15;
            const int pbase = hl * LCOLS + wl;
#pragma unroll
            for (int f = 0; f < 5; ++f) {
                const int pixel = pbase + doff[f];
                const int half  = q ^ ((pixel >> 2) & 1);
                const short8 b  = *(const short8*)&lds[pixel * 16 + half * 8];
                acc[r][c4] = __builtin_amdgcn_mfma_f32_16x16x32_bf16(afrag[f], b, acc[r][c4], 0, 0, 0);
            }
        }
    }

    float* on = out + (size_t)n * CO * IH * IW;
#pragma unroll
    for (int r = 0; r < 4; ++r) {
        const int gh = hbase + wave * 4 + r;
#pragma unroll
        for (int c4 = 0; c4 < 2; ++c4) {
            const int gw = wbase + c4 * 16 + l15;
#pragma unroll
            for (int reg = 0; reg < 4; ++reg) {
                const int co = quad * 4 + reg;
                on[((size_t)co * IH + gh) * IW + gw] = acc[r][c4][reg];
            }
        }
    }
}

extern "C" void kernel_launch(void* const* d_in, const int* in_sizes, int n_in,
                              void* d_out, int out_size, void* d_ws, size_t ws_size,
                              hipStream_t stream) {
    const float* x = (const float*)d_in[0];
    const float* w = (const float*)d_in[1];
    float* out     = (float*)d_out;

    if (ws_size >= WS_NEED) {
        dim3 gprep(2048);                       // 524,288 threads, 1 chunk each
        conv_prep<<<gprep, dim3(256), 0, stream>>>(x, w, (char*)d_ws);
        dim3 gconv((IW / TW) * (IH / TH) * 8);  // 4096 blocks, 1D swizzled
        conv3x3_lds<<<gconv, dim3(256), 0, stream>>>((const char*)d_ws, out);
    } else {
        dim3 grid((IW / TW) * (IH / TH) * 8);
        conv3x3_mfma_fb<<<grid, dim3(256), 0, stream>>>(x, w, out);
    }
}

// Round 4
// 296.572 us; speedup vs baseline: 1.0066x; 1.0066x over previous
//
#include <hip/hip_runtime.h>
#include <hip/hip_bf16.h>

// Conv2D 3x3 s1 p1: x[8,16,512,512] f32, w[16,144] f32 -> out[8,16,512,512] f32
//
// Implicit GEMM on bf16 MFMA (16x16x32), k = tap*16 + ci (K=144 pad 160).
// LDS tile: channels-last bf16 [18][66][16], 8B-slot swizzle slot=cg4^((pixel>>1)&2)
//   -> ds_read_b128 gives 8 contiguous channels (half = q ^ ((pixel>>2)&1)).
// R7 (post R4-R6 lessons): single kernel, TW=64 (R3 geometry — best dispatch,
//   traffic-optimal). The R3 bottleneck was SERIALIZED staging (load->store per
//   item = ~5 exposed HBM roundtrips, VGPR=52). Fix: issue ALL of items 0-3
//   (64 payload VGPRs) + halo loads before any store; item 4 chains into v0
//   after store0, its latency hidden under stores 1-3 + the weight-fragment
//   build (moved into the load shadow). __launch_bounds__(256,4) = 128-VGPR
//   budget (R4 taught: (256,8)'s 64-cap spills; tripwire = WRITE_SIZE).
//   Plus R5's proven XCD swizzle: image = bid&7 (one image per XCD under
//   round-robin dispatch), bx fastest -> halo lines L2-resident (fetch 134->118).
//   No d_ws: R6 showed workspace use triggers a ~81us 512MiB re-poison fill.

#define IH 512
#define IW 512
#define CI 16
#define CO 16
#define TH 16
#define TW 64
#define LROWS (TH + 2)   // 18
#define LCOLS (TW + 2)   // 66
#define NITEMS (LROWS * (TW / 4) * 4)   // 1152 interior staging items

typedef short short8  __attribute__((ext_vector_type(8)));
typedef short short4v __attribute__((ext_vector_type(4)));
typedef float f32x4   __attribute__((ext_vector_type(4)));

__device__ __forceinline__ short f32_to_bf16_bits(float v) {
    __hip_bfloat16 b = __float2bfloat16(v);   // RNE
    return __builtin_bit_cast(short, b);
}

struct ItemInfo {
    const float* src;
    int pb;      // pixel base = row*LCOLS + 1 + 4*wseg
    int ws;      // wseg
    int cg;      // channel group (4 ch)
    bool ok;     // row in bounds
};

__device__ __forceinline__ ItemInfo item_info(int i, int hbase, int wbase,
                                              const float* __restrict__ xn) {
    ItemInfo t;
    t.ws = i & 15;            // 16 wsegs of 4 cols
    t.cg = (i >> 4) & 3;
    const int row = i >> 6;   // 0..17
    const int gh  = hbase - 1 + row;
    t.ok  = (unsigned)gh < (unsigned)IH;
    t.src = xn + ((size_t)(t.cg * 4) * IH + gh) * IW + (wbase + 4 * t.ws);
    t.pb  = row * LCOLS + 1 + 4 * t.ws;
    return t;
}

__device__ __forceinline__ void item_load(const ItemInfo& t, f32x4 v[4]) {
    if (t.ok) {
#pragma unroll
        for (int jj = 0; jj < 4; ++jj)
            v[jj] = *(const f32x4*)(t.src + (size_t)jj * IH * IW);
    }
}

__device__ __forceinline__ void item_store(const ItemInfo& t, const f32x4 v[4],
                                           short* lds) {
    short4v pk[4];
    if (t.ok) {
#pragma unroll
        for (int j = 0; j < 4; ++j)
#pragma unroll
            for (int jj = 0; jj < 4; ++jj)
                pk[j][jj] = f32_to_bf16_bits(v[jj][j]);   // 4x4 transpose
    } else {
#pragma unroll
        for (int j = 0; j < 4; ++j) pk[j] = (short4v){0, 0, 0, 0};
    }
#pragma unroll
    for (int k = 0; k < 4; ++k) {
        const int j     = (k + t.ws) & 3;      // rotate: spread pixel phase -> banks
        const int pixel = t.pb + j;
        const int slot  = t.cg ^ ((pixel >> 1) & 2);
        *(short4v*)&lds[pixel * 16 + slot * 4] = pk[j];
    }
}

__global__ __launch_bounds__(256, 4)
void conv3x3_mfma(const float* __restrict__ x, const float* __restrict__ wgt,
                  float* __restrict__ out) {
    __shared__ short lds[LROWS * LCOLS * CI];   // 18*66*16*2 = 38,016 B

    const int tid  = threadIdx.x;
    const int wave = tid >> 6;
    const int lane = tid & 63;
    const int quad = lane >> 4;
    const int l15  = lane & 15;

    // XCD swizzle: image = bid&7 (one image per XCD), then bx fastest, then by
    const int bid   = blockIdx.x;
    const int n     = bid & 7;
    const int t     = bid >> 3;
    const int wbase = (t & 7) * TW;      // 8 tiles in x
    const int hbase = (t >> 3) * TH;     // 32 tiles in y

    const float* xn = x + (size_t)n * CI * IH * IW;

    // ---- staging: 1152 items, 4 issued fully in parallel + 1 chained ----
    // item: 4x global_load_dwordx4 (ch cg*4..+3, w gw..gw+3) -> 4x4 transpose ->
    //       4x ds_write_b64 in wseg-rotated order
    ItemInfo t0 = item_info(tid,       hbase, wbase, xn);
    ItemInfo t1 = item_info(tid + 256, hbase, wbase, xn);
    ItemInfo t2 = item_info(tid + 512, hbase, wbase, xn);
    ItemInfo t3 = item_info(tid + 768, hbase, wbase, xn);
    f32x4 v0[4], v1[4], v2[4], v3[4];
    item_load(t0, v0);        // all 16 dwordx4 in flight before any consume
    item_load(t1, v1);
    item_load(t2, v2);
    item_load(t3, v3);

    // halo cols c=0,65 (18 rows x 2 cols x 4 cgroups = 144 items): issue loads now
    const bool halo = tid < 144;
    float hv0 = 0.f, hv1 = 0.f, hv2 = 0.f, hv3 = 0.f;
    int hpix = 0, hslot = 0;
    if (halo) {
        const int cg4  = tid & 3;
        const int col2 = (tid >> 2) & 1;
        const int row  = tid >> 3;              // 0..17
        const int c    = col2 ? (LCOLS - 1) : 0;
        const int gh   = hbase - 1 + row;
        const int gw   = wbase - 1 + c;         // wbase-1 or wbase+64
        const bool ok  = ((unsigned)gh < (unsigned)IH) && ((unsigned)gw < (unsigned)IW);
        if (ok) {
            const float* hs = xn + ((size_t)(cg4 * 4) * IH + gh) * IW + gw;
            hv0 = hs[0];
            hv1 = hs[(size_t)IH * IW];
            hv2 = hs[(size_t)2 * IH * IW];
            hv3 = hs[(size_t)3 * IH * IW];
        }
        hpix  = row * LCOLS + c;
        hslot = cg4 ^ ((hpix >> 1) & 2);
    }

    item_store(t0, v0, lds);                    // frees v0

    // item 4 (tid<128): chain into v0; latency hides under stores 1-3 + afrag
    const bool act4 = tid < (NITEMS - 1024);    // tid < 128
    ItemInfo t4 = item_info(act4 ? (1024 + tid) : tid, hbase, wbase, xn);
    if (act4) item_load(t4, v0);

    // A fragments: W[co=l15][k], k = f*32 + quad*8 + j; zero for k>=144.
    // L2-hot scalar loads — VALU+SMEM work that fills the load shadow.
    short8 afrag[5];
#pragma unroll
    for (int f = 0; f < 5; ++f) {
#pragma unroll
        for (int j = 0; j < 8; ++j) {
            const int k = f * 32 + quad * 8 + j;
            float val = 0.0f;
            if (k < 144) {
                const int ci  = k & 15;
                const int tap = k >> 4;
                val = wgt[l15 * 144 + ci * 9 + tap];
            }
            afrag[f][j] = f32_to_bf16_bits(val);
        }
    }

    item_store(t1, v1, lds);
    item_store(t2, v2, lds);
    item_store(t3, v3, lds);
    if (act4) item_store(t4, v0, lds);
    if (halo) {
        short4v pk;
        pk[0] = f32_to_bf16_bits(hv0);
        pk[1] = f32_to_bf16_bits(hv1);
        pk[2] = f32_to_bf16_bits(hv2);
        pk[3] = f32_to_bf16_bits(hv3);
        *(short4v*)&lds[hpix * 16 + hslot * 4] = pk;
    }
    __syncthreads();

    // ---- per-f tap offsets (depend only on quad) ----
    const int q = quad & 1;
    int doff[5];
#pragma unroll
    for (int f = 0; f < 5; ++f) {
        const int tap = (f < 4) ? (f * 2 + (quad >> 1)) : 8;
        const int kh  = tap / 3;
        const int kw  = tap - kh * 3;
        doff[f] = kh * LCOLS + kw;
    }

    // ---- MFMA main: 4 h-rows x 4 w-segments per wave, 5 K-steps each ----
    f32x4 acc[4][4];
#pragma unroll
    for (int r = 0; r < 4; ++r)
#pragma unroll
        for (int c4 = 0; c4 < 4; ++c4)
            acc[r][c4] = (f32x4){0.f, 0.f, 0.f, 0.f};

#pragma unroll
    for (int r = 0; r < 4; ++r) {
        const int hl = wave * 4 + r;
#pragma unroll
        for (int c4 = 0; c4 < 4; ++c4) {
            const int wl    = c4 * 16 + l15;
            const int pbase = hl * LCOLS + wl;
#pragma unroll
            for (int f = 0; f < 5; ++f) {
                const int pixel = pbase + doff[f];
                const int half  = q ^ ((pixel >> 2) & 1);
                const short8 b  = *(const short8*)&lds[pixel * 16 + half * 8]; // ds_read_b128
                acc[r][c4] = __builtin_amdgcn_mfma_f32_16x16x32_bf16(afrag[f], b, acc[r][c4], 0, 0, 0);
            }
        }
    }

    // ---- store: C/D col = l15 = pixel, row = quad*4+reg = co ----
    float* on = out + (size_t)n * CO * IH * IW;
#pragma unroll
    for (int r = 0; r < 4; ++r) {
        const int gh = hbase + wave * 4 + r;
#pragma unroll
        for (int c4 = 0; c4 < 4; ++c4) {
            const int gw = wbase + c4 * 16 + l15;
#pragma unroll
            for (int reg = 0; reg < 4; ++reg) {
                const int co = quad * 4 + reg;
                on[((size_t)co * IH + gh) * IW + gw] = acc[r][c4][reg];
            }
        }
    }
}

extern "C" void kernel_launch(void* const* d_in, const int* in_sizes, int n_in,
                              void* d_out, int out_size, void* d_ws, size_t ws_size,
                              hipStream_t stream) {
    const float* x = (const float*)d_in[0];
    const float* w = (const float*)d_in[1];
    float* out     = (float*)d_out;

    dim3 grid((IW / TW) * (IH / TH) * 8);   // 8*32*8 = 2048 blocks, 1D swizzled
    dim3 block(256);
    conv3x3_mfma<<<grid, block, 0, stream>>>(x, w, out);
}